// Round 12
// baseline (147.204 us; speedup 1.0000x reference)
//
#include <hip/hip_runtime.h>

#define NB 4
#define NPRI 3106
#define NC 21
#define NCLS 20
#define KMAX 200
#define NMAX 1024   /* candidate capacity per (image,class) */
#define WMAX 16     /* NMAX/64 */
#define TMAX (WMAX*(WMAX+1)/2)   /* 136 triangular 64x64 tiles */
#define MIN_SC 0.05f
#define MAX_OV 0.45f

/* ---- workspace layout (float-element offsets; u64 arrays at even offsets) ---- */
#define F_PROBS 0                                  /* NB*NCLS*NPRI floats        */
#define F_KEYS  (F_PROBS + NB*NCLS*NPRI)           /* NB*NCLS*NMAX u64 (sorted)  */
#define F_BOXES (F_KEYS + NB*NCLS*NMAX*2)          /* NB*NCLS*NMAX float4        */
#define F_AREAS (F_BOXES + NB*NCLS*NMAX*4)         /* NB*NCLS*NMAX floats        */
#define F_NCAND (F_AREAS + NB*NCLS*NMAX)           /* NB*NCLS ints (pad to 128)  */
#define F_M     (F_NCAND + 128)                    /* NB*NCLS*WMAX*NMAX u64      */
#define F_POOL  (F_M + NB*NCLS*WMAX*NMAX*2)        /* NB*NCLS*KMAX u64           */
#define F_CNT   (F_POOL + NB*NCLS*KMAX*2)          /* NB*NCLS ints               */
#define F_DONE  (F_CNT + NB*NCLS)                  /* NB ints (per-image done)   */

/* ---- output layout (floats) ---- */
#define OUT_BOXES  0
#define OUT_LABELS (NB*KMAX*4)
#define OUT_SCORES (OUT_LABELS + NB*KMAX)
#define OUT_COUNTS (OUT_SCORES + NB*KMAX)

__device__ __forceinline__ void decode_box(const float* __restrict__ locs,
                                           const float* __restrict__ priors,
                                           int b, int pi,
                                           float& x1, float& y1, float& x2, float& y2) {
    const float* l  = locs + ((size_t)b * NPRI + pi) * 4;
    const float* pr = priors + (size_t)pi * 4;
    float pcx = pr[0], pcy = pr[1], pw = pr[2], ph = pr[3];
    /* reference op order: (l*pw)/10 + pcx ; exp(l/5)*pw ; cx -/+ w/2 */
    float cx = l[0] * pw / 10.0f + pcx;
    float cy = l[1] * ph / 10.0f + pcy;
    float w  = expf(l[2] / 5.0f) * pw;
    float h  = expf(l[3] / 5.0f) * ph;
    x1 = cx - w / 2.0f;  y1 = cy - h / 2.0f;
    x2 = cx + w / 2.0f;  y2 = cy + h / 2.0f;
}

__device__ __forceinline__ unsigned long long shfl_xor_u64(unsigned long long v, int m) {
    unsigned lo = (unsigned)v, hi = (unsigned)(v >> 32);
    lo = __shfl_xor(lo, m);
    hi = __shfl_xor(hi, m);
    return ((unsigned long long)hi << 32) | lo;
}

/* K0 (R0 proven, VERBATIM + done[b] zero-init in block 0 — stream-ordered
   before det_finish's acquire, re-zeroed every iteration so workspace
   re-poisoning is harmless): softmax once per (b,p); coalesced LDS stage. */
__global__ __launch_bounds__(256)
void det_softmax(const float* __restrict__ scores, float* __restrict__ ws) {
    if (blockIdx.x == 0 && threadIdx.x < NB)
        ((int*)(ws + F_DONE))[threadIdx.x] = 0;

    __shared__ float row[256 * NC];
    const int t0 = blockIdx.x * 256;
    int items = NB * NPRI - t0; if (items > 256) items = 256;
    const int cntf = items * NC;
    for (int i = threadIdx.x; i < cntf; i += 256)
        row[i] = scores[(size_t)t0 * NC + i];
    __syncthreads();
    const int t = t0 + threadIdx.x;
    if (t >= NB * NPRI) return;
    const int b = t / NPRI, p = t - b * NPRI;
    const float* s = row + threadIdx.x * NC;
    float m = -1e30f;
    #pragma unroll
    for (int c = 0; c < NC; ++c) m = fmaxf(m, s[c]);
    float e[NC]; float sum = 0.0f;
    #pragma unroll
    for (int c = 0; c < NC; ++c) { e[c] = expf(s[c] - m); sum += e[c]; }
    #pragma unroll
    for (int c = 1; c < NC; ++c)
        ws[F_PROBS + ((size_t)(b * NCLS + (c - 1)) * NPRI + p)] = e[c] / sum;
}

/* K1 (R10 proven, VERBATIM): per (image,class) block loads its class's prob
   row (coalesced), thresholds, LDS-compacts, register-resident bitonic
   (j<=32 via shfl_xor, j>=64 via LDS; full 1024 network with ~0ull padding
   == npow network on first n outputs), decodes. */
__global__ __launch_bounds__(1024)
void det_prep(const float* __restrict__ locs, const float* __restrict__ priors,
              float* __restrict__ ws) {
    const int bc  = blockIdx.x;
    const int b   = bc / NCLS;
    const int tid = threadIdx.x;

    __shared__ unsigned long long keys[NMAX];   /* 8192 B */
    __shared__ int n_sh;
    if (tid == 0) n_sh = 0;
    __syncthreads();

    const float* prob = ws + F_PROBS + (size_t)bc * NPRI;
    for (int p = tid; p < NPRI; p += 1024) {
        float s = prob[p];
        if (s > MIN_SC) {
            int idx = atomicAdd(&n_sh, 1);
            if (idx < NMAX) {
                unsigned int sb = __float_as_uint(s);
                keys[idx] = ((unsigned long long)(~sb) << 32) | (unsigned int)p;
            }
        }
    }
    __syncthreads();
    int n = n_sh; if (n > NMAX) n = NMAX;

    unsigned long long mykey = (tid < n) ? keys[tid] : ~0ull;
    __syncthreads();   /* keys[] reused as the exchange buffer below */
    for (int k = 2; k <= NMAX; k <<= 1) {
        for (int j = k >> 1; j > 0; j >>= 1) {
            unsigned long long other;
            if (j >= 64) {
                keys[tid] = mykey;
                __syncthreads();
                other = keys[tid ^ j];
                __syncthreads();
            } else {
                other = shfl_xor_u64(mykey, j);
            }
            bool lower    = (tid & j) == 0;     /* I hold the smaller index */
            bool up       = (tid & k) == 0;
            bool take_min = (lower == up);
            bool swap     = take_min ? (other < mykey) : (other > mykey);
            mykey = swap ? other : mykey;
        }
    }

    if (tid == 0) ((int*)(ws + F_NCAND))[bc] = n;
    unsigned long long* gk = (unsigned long long*)(ws + F_KEYS) + (size_t)bc * NMAX;
    float4* gb = (float4*)(ws + F_BOXES) + (size_t)bc * NMAX;
    float*  ga = ws + F_AREAS + (size_t)bc * NMAX;
    if (tid < n) {
        gk[tid] = mykey;
        int pi = (int)(mykey & 0xFFFFFFFFull);
        float x1, y1, x2, y2;
        decode_box(locs, priors, b, pi, x1, y1, x2, y2);
        gb[tid] = make_float4(x1, y1, x2, y2);
        ga[tid] = (x2 - x1) * (y2 - y1);
    }
}

/* K2 (R8 proven, VERBATIM): 64x64-tile / two-column-chain / divide-free +
   near-band (bit-identical M); column broadcasts via wave-private LDS
   uniform-address reads on the idle LDS pipe (R8: mbuild 46 -> <41).
   Issue-bound; do not touch the inner body. */
__global__ __launch_bounds__(256)
void det_mbuild(float* __restrict__ ws) {
    const int bc = blockIdx.y;
    const int t  = blockIdx.x * 4 + (threadIdx.x >> 6);
    if (t >= TMAX) return;
    const int wv   = threadIdx.x >> 6;
    const int lane = threadIdx.x & 63;
    int tj = 0;
    while ((tj + 1) * (tj + 2) / 2 <= t) ++tj;   /* wave-uniform decode */
    const int w = t - tj * (tj + 1) / 2;          /* w <= tj */
    const int n = ((const int*)(ws + F_NCAND))[bc];
    const int bi0 = w * 64, bj0 = tj * 64;
    if (bj0 >= n) return;

    __shared__ float4 wbox[4][64];   /* 4 KB: per-wave j-tile boxes   */
    __shared__ float  warea[4][64];  /* 1 KB: per-wave j-tile areas   */

    const float4* bx = (const float4*)(ws + F_BOXES) + (size_t)bc * NMAX;
    const float*  ar = ws + F_AREAS + (size_t)bc * NMAX;
    const float4 bi = bx[bi0 + lane];
    const float  ai = ar[bi0 + lane];
    wbox[wv][lane]  = bx[bj0 + lane];
    warea[wv][lane] = ar[bj0 + lane];
    const unsigned long long vm =
        (n - bi0 >= 64) ? ~0ull : ((1ull << (n - bi0)) - 1ull);
    const bool diag = (w == tj);
    unsigned long long myword = 0ull;

    const float4* __restrict__ jb = wbox[wv];
    const float*  __restrict__ ja = warea[wv];

    #pragma unroll
    for (int jj = 0; jj < 64; jj += 2) {
        float4 ca = jb[jj];         /* uniform-addr ds_read_b128 = broadcast */
        float  aau = ja[jj];        /* uniform-addr ds_read_b32              */
        float4 cb = jb[jj + 1];
        float  bau = ja[jj + 1];

        float alx = fmaxf(bi.x, ca.x), aly = fmaxf(bi.y, ca.y);
        float arx = fminf(bi.z, ca.z), ary = fminf(bi.w, ca.w);
        float blx = fmaxf(bi.x, cb.x), bly = fmaxf(bi.y, cb.y);
        float brx = fminf(bi.z, cb.z), bry = fminf(bi.w, cb.w);
        float adx = fmaxf(arx - alx, 0.0f), ady = fmaxf(ary - aly, 0.0f);
        float bdx = fmaxf(brx - blx, 0.0f), bdy = fmaxf(bry - bly, 0.0f);
        float ain = adx * ady;
        float bin = bdx * bdy;
        float au  = ai + aau - ain;           /* union > 0 (areas positive) */
        float bu  = ai + bau - bin;
        float at  = MAX_OV * au;
        float bt  = MAX_OV * bu;
        bool akeep = ain > at;
        bool bkeep = bin > bt;
        bool anear = fabsf(ain - at) <= at * 6e-7f;
        bool bnear = fabsf(bin - bt) <= bt * 6e-7f;
        if (__ballot(anear || bnear)) {       /* rare: exact ref-order divide */
            float aio = ain / au;
            float bio = bin / bu;
            akeep = anear ? (aio > MAX_OV) : akeep;
            bkeep = bnear ? (bio > MAX_OV) : bkeep;
        }
        unsigned long long abits = __ballot(akeep) & vm;
        unsigned long long bbits = __ballot(bkeep) & vm;
        if (diag) {
            abits &= (1ull << jj) - 1ull;      /* i < j on diagonal tile */
            bbits &= (1ull << (jj + 1)) - 1ull;
        }
        if (lane == jj)     myword = abits;
        if (lane == jj + 1) myword = bbits;
    }
    if (bj0 + lane < n)
        ((unsigned long long*)(ws + F_M))
            [((size_t)bc * WMAX + w) * NMAX + bj0 + lane] = myword;
}

/* K3 (R0 proven, VERBATIM — merged finish): resolve (wave 0) + zero-fill +
   release/acquire via done[b], then per-class rank-select topk. Runs alone
   after mbuild — its 80-block done-spin has nothing to starve (proven benign
   in R0/R2/R3; R1's failure was 2720 CONCURRENT tile blocks, not this).
   R11: replaces the finishA/finishB split to drop one kernel boundary. */
__global__ __launch_bounds__(256)
void det_finish(const float* __restrict__ locs, const float* __restrict__ priors,
                float* __restrict__ ws, float* __restrict__ out) {
    const int bc   = blockIdx.x;
    const int b    = bc / NCLS;
    const int c    = bc - b * NCLS;       /* 0..19 */
    const int cls  = c + 1;
    const int tid  = threadIdx.x;
    int* done_i = (int*)(ws + F_DONE);

    if (tid < 64) {
        const int lane = tid;
        const int n    = ((const int*)(ws + F_NCAND))[bc];
        const unsigned long long* Mb =
            (const unsigned long long*)(ws + F_M) + (size_t)bc * WMAX * NMAX;

        unsigned long long kw[WMAX];
        #pragma unroll
        for (int w = 0; w < WMAX; ++w) kw[w] = 0ull;

        const unsigned long long lmask = (1ull << lane) - 1ull;
        #pragma unroll
        for (int w = 0; w < WMAX; ++w) {
            if (w * 64 < n) {
                int cc = w * 64 + lane;
                bool valid = cc < n;
                unsigned long long pre = 0ull;
                #pragma unroll
                for (int v = 0; v < WMAX; ++v)
                    if (v < w) pre |= Mb[(size_t)v * NMAX + cc] & kw[v];
                unsigned long long dg = Mb[(size_t)w * NMAX + cc] & lmask;
                bool sup0 = (pre != 0ull);
                unsigned long long K = __ballot(valid && !sup0);
                for (int it = 0; it < 64; ++it) {
                    bool sup = sup0 || ((dg & K) != 0ull);
                    unsigned long long Kn = __ballot(valid && !sup);
                    if (Kn == K) break;
                    K = Kn;
                }
                kw[w] = K;
            }
        }

        int pref[WMAX + 1];
        pref[0] = 0;
        #pragma unroll
        for (int w = 0; w < WMAX; ++w) pref[w + 1] = pref[w] + __popcll(kw[w]);
        if (lane == 0) ((int*)(ws + F_CNT))[bc] = pref[WMAX];

        const unsigned long long* gk =
            (const unsigned long long*)(ws + F_KEYS) + (size_t)bc * NMAX;
        unsigned long long* pool =
            (unsigned long long*)(ws + F_POOL) + (size_t)bc * KMAX;
        const unsigned long long ctag = (unsigned long long)(cls << 12);
        #pragma unroll
        for (int w = 0; w < WMAX; ++w) {
            unsigned long long kwv = kw[w];
            int cc = w * 64 + lane;
            if (cc < n && ((kwv >> lane) & 1ull)) {
                int pos = pref[w] + __popcll(kwv & lmask);
                if (pos < KMAX) pool[pos] = gk[cc] | ctag;
            }
        }
    }

    /* zero image b's output slice, partitioned over its 20 blocks */
    {
        int idx = c * 256 + tid;
        if (idx < KMAX * 4) {
            out[OUT_BOXES + (size_t)b * KMAX * 4 + idx] = 0.0f;
        } else if (idx < KMAX * 4 + KMAX) {
            out[OUT_LABELS + b * KMAX + (idx - KMAX * 4)] = 0.0f;
        } else if (idx < KMAX * 4 + 2 * KMAX) {
            out[OUT_SCORES + b * KMAX + (idx - KMAX * 4 - KMAX)] = 0.0f;
        }
    }

    __threadfence();
    __syncthreads();
    if (tid == 0)
        __hip_atomic_fetch_add(done_i + b, 1, __ATOMIC_RELEASE,
                               __HIP_MEMORY_SCOPE_AGENT);

    if (tid == 0) {
        int it = 0;
        while (__hip_atomic_load(done_i + b, __ATOMIC_ACQUIRE,
                                 __HIP_MEMORY_SCOPE_AGENT) < NCLS
               && it < (1 << 20)) ++it;
    }
    __syncthreads();

    __shared__ unsigned long long lpool[NCLS * KMAX];  /* 32 KB */
    __shared__ int cnts[NCLS];

    const int* cnt = (const int*)(ws + F_CNT);
    if (tid < NCLS) cnts[tid] = cnt[b * NCLS + tid];
    __syncthreads();

    const unsigned long long* pool =
        (const unsigned long long*)(ws + F_POOL) + (size_t)b * NCLS * KMAX;
    for (int i = tid; i < NCLS * KMAX; i += 256) {
        int c2 = i / KMAX, r = i - c2 * KMAX;
        int mc2 = cnts[c2] < KMAX ? cnts[c2] : KMAX;
        lpool[i] = (r < mc2) ? pool[i] : ~0ull;
    }
    __syncthreads();

    if (c == 0 && tid == 0) {
        int tot = 0;
        for (int c2 = 0; c2 < NCLS; ++c2) tot += cnts[c2];
        int count = tot < KMAX ? tot : KMAX;
        if (tot == 0) {
            float* ob = out + OUT_BOXES + (size_t)b * KMAX * 4;
            ob[0] = 0.0f; ob[1] = 0.0f; ob[2] = 1.0f; ob[3] = 1.0f;
            count = 1;
        }
        out[OUT_COUNTS + b] = (float)count;
    }

    const int mc = cnts[c] < KMAX ? cnts[c] : KMAX;
    if (tid < mc) {
        unsigned long long key = lpool[c * KMAX + tid];
        int rank = 0;
        #pragma unroll
        for (int c2 = 0; c2 < NCLS; ++c2) {
            int lo = 0, hi = KMAX;
            #pragma unroll
            for (int s = 0; s < 8; ++s) {          /* ceil(log2(201)) = 8 */
                int mid = (lo + hi) >> 1;
                int midc = mid < KMAX ? mid : KMAX - 1;
                unsigned long long v = lpool[c2 * KMAX + midc];
                bool lt = (lo < hi) && (v < key);
                lo = lt ? mid + 1 : lo;
                hi = lt ? hi : mid;
            }
            rank += lo;
        }
        if (rank < KMAX) {
            unsigned int lo32 = (unsigned int)key;
            int pi  = lo32 & 0xFFF;
            int lab = (lo32 >> 12) & 0x1F;
            float sc = __uint_as_float(~(unsigned int)(key >> 32));
            float x1, y1, x2, y2;
            decode_box(locs, priors, b, pi, x1, y1, x2, y2);
            float* ob = out + OUT_BOXES + ((size_t)b * KMAX + rank) * 4;
            ob[0] = x1; ob[1] = y1; ob[2] = x2; ob[3] = y2;
            out[OUT_LABELS + b * KMAX + rank] = (float)lab;
            out[OUT_SCORES + b * KMAX + rank] = sc;
        }
    }
}

extern "C" void kernel_launch(void* const* d_in, const int* in_sizes, int n_in,
                              void* d_out, int out_size, void* d_ws, size_t ws_size,
                              hipStream_t stream) {
    const float* locs   = (const float*)d_in[0];
    const float* scores = (const float*)d_in[1];
    const float* priors = (const float*)d_in[2];
    float* out = (float*)d_out;
    float* ws  = (float*)d_ws;

    det_softmax<<<(NB * NPRI + 255) / 256, 256, 0, stream>>>(scores, ws);
    det_prep<<<NB * NCLS, 1024, 0, stream>>>(locs, priors, ws);
    det_mbuild<<<dim3((TMAX + 3) / 4, NB * NCLS), 256, 0, stream>>>(ws);
    det_finish<<<NB * NCLS, 256, 0, stream>>>(locs, priors, ws, out);
}

// Round 15
// 140.089 us; speedup vs baseline: 1.0508x; 1.0508x over previous
//
#include <hip/hip_runtime.h>

#define NB 4
#define NPRI 3106
#define NC 21
#define NCLS 20
#define KMAX 200
#define NMAX 1024   /* candidate capacity per (image,class) */
#define WMAX 16     /* NMAX/64 */
#define TMAX (WMAX*(WMAX+1)/2)   /* 136 triangular 64x64 tiles */
#define MIN_SC 0.05f
#define MAX_OV 0.45f

/* ---- workspace layout (float-element offsets; u64 arrays at even offsets) ---- */
#define F_PROBS 0                                  /* NB*NCLS*NPRI floats        */
#define F_KEYS  (F_PROBS + NB*NCLS*NPRI)           /* NB*NCLS*NMAX u64 (sorted)  */
#define F_BOXES (F_KEYS + NB*NCLS*NMAX*2)          /* NB*NCLS*NMAX float4        */
#define F_AREAS (F_BOXES + NB*NCLS*NMAX*4)         /* NB*NCLS*NMAX floats        */
#define F_NCAND (F_AREAS + NB*NCLS*NMAX)           /* NB*NCLS ints (pad to 128)  */
#define F_M     (F_NCAND + 128)                    /* NB*NCLS*WMAX*NMAX u64      */
#define F_POOL  (F_M + NB*NCLS*WMAX*NMAX*2)        /* NB*NCLS*KMAX u64           */
#define F_CNT   (F_POOL + NB*NCLS*KMAX*2)          /* NB*NCLS ints               */
#define F_DONE  (F_CNT + NB*NCLS)                  /* NB ints (unused)           */

/* ---- output layout (floats) ---- */
#define OUT_BOXES  0
#define OUT_LABELS (NB*KMAX*4)
#define OUT_SCORES (OUT_LABELS + NB*KMAX)
#define OUT_COUNTS (OUT_SCORES + NB*KMAX)

__device__ __forceinline__ void decode_box(const float* __restrict__ locs,
                                           const float* __restrict__ priors,
                                           int b, int pi,
                                           float& x1, float& y1, float& x2, float& y2) {
    const float* l  = locs + ((size_t)b * NPRI + pi) * 4;
    const float* pr = priors + (size_t)pi * 4;
    float pcx = pr[0], pcy = pr[1], pw = pr[2], ph = pr[3];
    /* reference op order: (l*pw)/10 + pcx ; exp(l/5)*pw ; cx -/+ w/2 */
    float cx = l[0] * pw / 10.0f + pcx;
    float cy = l[1] * ph / 10.0f + pcy;
    float w  = expf(l[2] / 5.0f) * pw;
    float h  = expf(l[3] / 5.0f) * ph;
    x1 = cx - w / 2.0f;  y1 = cy - h / 2.0f;
    x2 = cx + w / 2.0f;  y2 = cy + h / 2.0f;
}

__device__ __forceinline__ unsigned long long shfl_xor_u64(unsigned long long v, int m) {
    unsigned lo = (unsigned)v, hi = (unsigned)(v >> 32);
    lo = __shfl_xor(lo, m);
    hi = __shfl_xor(hi, m);
    return ((unsigned long long)hi << 32) | lo;
}

/* K0 (R0 proven, VERBATIM): softmax once per (b,p); coalesced LDS stage.
   Part of the best measured config (R10, 140.65 us). */
__global__ __launch_bounds__(256)
void det_softmax(const float* __restrict__ scores, float* __restrict__ ws) {
    __shared__ float row[256 * NC];
    const int t0 = blockIdx.x * 256;
    int items = NB * NPRI - t0; if (items > 256) items = 256;
    const int cntf = items * NC;
    for (int i = threadIdx.x; i < cntf; i += 256)
        row[i] = scores[(size_t)t0 * NC + i];
    __syncthreads();
    const int t = t0 + threadIdx.x;
    if (t >= NB * NPRI) return;
    const int b = t / NPRI, p = t - b * NPRI;
    const float* s = row + threadIdx.x * NC;
    float m = -1e30f;
    #pragma unroll
    for (int c = 0; c < NC; ++c) m = fmaxf(m, s[c]);
    float e[NC]; float sum = 0.0f;
    #pragma unroll
    for (int c = 0; c < NC; ++c) { e[c] = expf(s[c] - m); sum += e[c]; }
    #pragma unroll
    for (int c = 1; c < NC; ++c)
        ws[F_PROBS + ((size_t)(b * NCLS + (c - 1)) * NPRI + p)] = e[c] / sum;
}

/* K1 (R10 proven, VERBATIM): per (image,class) block loads its class's prob
   row (coalesced), thresholds, LDS-compacts, register-resident bitonic
   (j<=32 via shfl_xor, j>=64 via LDS; full 1024 network with ~0ull padding
   == npow network on first n outputs), decodes. */
__global__ __launch_bounds__(1024)
void det_prep(const float* __restrict__ locs, const float* __restrict__ priors,
              float* __restrict__ ws) {
    const int bc  = blockIdx.x;
    const int b   = bc / NCLS;
    const int tid = threadIdx.x;

    __shared__ unsigned long long keys[NMAX];   /* 8192 B */
    __shared__ int n_sh;
    if (tid == 0) n_sh = 0;
    __syncthreads();

    const float* prob = ws + F_PROBS + (size_t)bc * NPRI;
    for (int p = tid; p < NPRI; p += 1024) {
        float s = prob[p];
        if (s > MIN_SC) {
            int idx = atomicAdd(&n_sh, 1);
            if (idx < NMAX) {
                unsigned int sb = __float_as_uint(s);
                keys[idx] = ((unsigned long long)(~sb) << 32) | (unsigned int)p;
            }
        }
    }
    __syncthreads();
    int n = n_sh; if (n > NMAX) n = NMAX;

    unsigned long long mykey = (tid < n) ? keys[tid] : ~0ull;
    __syncthreads();   /* keys[] reused as the exchange buffer below */
    for (int k = 2; k <= NMAX; k <<= 1) {
        for (int j = k >> 1; j > 0; j >>= 1) {
            unsigned long long other;
            if (j >= 64) {
                keys[tid] = mykey;
                __syncthreads();
                other = keys[tid ^ j];
                __syncthreads();
            } else {
                other = shfl_xor_u64(mykey, j);
            }
            bool lower    = (tid & j) == 0;     /* I hold the smaller index */
            bool up       = (tid & k) == 0;
            bool take_min = (lower == up);
            bool swap     = take_min ? (other < mykey) : (other > mykey);
            mykey = swap ? other : mykey;
        }
    }

    if (tid == 0) ((int*)(ws + F_NCAND))[bc] = n;
    unsigned long long* gk = (unsigned long long*)(ws + F_KEYS) + (size_t)bc * NMAX;
    float4* gb = (float4*)(ws + F_BOXES) + (size_t)bc * NMAX;
    float*  ga = ws + F_AREAS + (size_t)bc * NMAX;
    if (tid < n) {
        gk[tid] = mykey;
        int pi = (int)(mykey & 0xFFFFFFFFull);
        float x1, y1, x2, y2;
        decode_box(locs, priors, b, pi, x1, y1, x2, y2);
        gb[tid] = make_float4(x1, y1, x2, y2);
        ga[tid] = (x2 - x1) * (y2 - y1);
    }
}

/* K2 (R8 proven, VERBATIM): 64x64-tile / two-column-chain / divide-free +
   near-band (bit-identical M); column broadcasts via wave-private LDS
   uniform-address reads on the idle LDS pipe (R8: mbuild 46 -> <41).
   Issue-bound; do not touch the inner body. R13/R14 writelane experiments
   failed to compile (no builtin; asm "s" constraint can't legalize
   VGPR-resident ballot values) — that path is closed, EV negative. */
__global__ __launch_bounds__(256)
void det_mbuild(float* __restrict__ ws) {
    const int bc = blockIdx.y;
    const int t  = blockIdx.x * 4 + (threadIdx.x >> 6);
    if (t >= TMAX) return;
    const int wv   = threadIdx.x >> 6;
    const int lane = threadIdx.x & 63;
    int tj = 0;
    while ((tj + 1) * (tj + 2) / 2 <= t) ++tj;   /* wave-uniform decode */
    const int w = t - tj * (tj + 1) / 2;          /* w <= tj */
    const int n = ((const int*)(ws + F_NCAND))[bc];
    const int bi0 = w * 64, bj0 = tj * 64;
    if (bj0 >= n) return;

    __shared__ float4 wbox[4][64];   /* 4 KB: per-wave j-tile boxes   */
    __shared__ float  warea[4][64];  /* 1 KB: per-wave j-tile areas   */

    const float4* bx = (const float4*)(ws + F_BOXES) + (size_t)bc * NMAX;
    const float*  ar = ws + F_AREAS + (size_t)bc * NMAX;
    const float4 bi = bx[bi0 + lane];
    const float  ai = ar[bi0 + lane];
    wbox[wv][lane]  = bx[bj0 + lane];
    warea[wv][lane] = ar[bj0 + lane];
    const unsigned long long vm =
        (n - bi0 >= 64) ? ~0ull : ((1ull << (n - bi0)) - 1ull);
    const bool diag = (w == tj);
    unsigned long long myword = 0ull;

    const float4* __restrict__ jb = wbox[wv];
    const float*  __restrict__ ja = warea[wv];

    #pragma unroll
    for (int jj = 0; jj < 64; jj += 2) {
        float4 ca = jb[jj];         /* uniform-addr ds_read_b128 = broadcast */
        float  aau = ja[jj];        /* uniform-addr ds_read_b32              */
        float4 cb = jb[jj + 1];
        float  bau = ja[jj + 1];

        float alx = fmaxf(bi.x, ca.x), aly = fmaxf(bi.y, ca.y);
        float arx = fminf(bi.z, ca.z), ary = fminf(bi.w, ca.w);
        float blx = fmaxf(bi.x, cb.x), bly = fmaxf(bi.y, cb.y);
        float brx = fminf(bi.z, cb.z), bry = fminf(bi.w, cb.w);
        float adx = fmaxf(arx - alx, 0.0f), ady = fmaxf(ary - aly, 0.0f);
        float bdx = fmaxf(brx - blx, 0.0f), bdy = fmaxf(bry - bly, 0.0f);
        float ain = adx * ady;
        float bin = bdx * bdy;
        float au  = ai + aau - ain;           /* union > 0 (areas positive) */
        float bu  = ai + bau - bin;
        float at  = MAX_OV * au;
        float bt  = MAX_OV * bu;
        bool akeep = ain > at;
        bool bkeep = bin > bt;
        bool anear = fabsf(ain - at) <= at * 6e-7f;
        bool bnear = fabsf(bin - bt) <= bt * 6e-7f;
        if (__ballot(anear || bnear)) {       /* rare: exact ref-order divide */
            float aio = ain / au;
            float bio = bin / bu;
            akeep = anear ? (aio > MAX_OV) : akeep;
            bkeep = bnear ? (bio > MAX_OV) : bkeep;
        }
        unsigned long long abits = __ballot(akeep) & vm;
        unsigned long long bbits = __ballot(bkeep) & vm;
        if (diag) {
            abits &= (1ull << jj) - 1ull;      /* i < j on diagonal tile */
            bbits &= (1ull << (jj + 1)) - 1ull;
        }
        if (lane == jj)     myword = abits;
        if (lane == jj + 1) myword = bbits;
    }
    if (bj0 + lane < n)
        ((unsigned long long*)(ws + F_M))
            [((size_t)bc * WMAX + w) * NMAX + bj0 + lane] = myword;
}

/* K3a (R4 proven, VERBATIM): resolve (wave 0) + pool/cnt writes + output
   zero-fill. No atomics, no spin — kernel boundary to K3b is the handshake.
   (R12 measured the merged spin-finish at +6.5 us vs this split: boundaries
   are the cheapest bulk sync on this chip. Do not re-merge.) */
__global__ __launch_bounds__(256)
void det_finishA(float* __restrict__ ws, float* __restrict__ out) {
    const int bc   = blockIdx.x;
    const int b    = bc / NCLS;
    const int c    = bc - b * NCLS;       /* 0..19 */
    const int cls  = c + 1;
    const int tid  = threadIdx.x;

    if (tid < 64) {
        const int lane = tid;
        const int n    = ((const int*)(ws + F_NCAND))[bc];
        const unsigned long long* Mb =
            (const unsigned long long*)(ws + F_M) + (size_t)bc * WMAX * NMAX;

        unsigned long long kw[WMAX];
        #pragma unroll
        for (int w = 0; w < WMAX; ++w) kw[w] = 0ull;

        const unsigned long long lmask = (1ull << lane) - 1ull;
        #pragma unroll
        for (int w = 0; w < WMAX; ++w) {
            if (w * 64 < n) {
                int cc = w * 64 + lane;
                bool valid = cc < n;
                unsigned long long pre = 0ull;
                #pragma unroll
                for (int v = 0; v < WMAX; ++v)
                    if (v < w) pre |= Mb[(size_t)v * NMAX + cc] & kw[v];
                unsigned long long dg = Mb[(size_t)w * NMAX + cc] & lmask;
                bool sup0 = (pre != 0ull);
                unsigned long long K = __ballot(valid && !sup0);
                for (int it = 0; it < 64; ++it) {
                    bool sup = sup0 || ((dg & K) != 0ull);
                    unsigned long long Kn = __ballot(valid && !sup);
                    if (Kn == K) break;
                    K = Kn;
                }
                kw[w] = K;
            }
        }

        int pref[WMAX + 1];
        pref[0] = 0;
        #pragma unroll
        for (int w = 0; w < WMAX; ++w) pref[w + 1] = pref[w] + __popcll(kw[w]);
        if (lane == 0) ((int*)(ws + F_CNT))[bc] = pref[WMAX];

        const unsigned long long* gk =
            (const unsigned long long*)(ws + F_KEYS) + (size_t)bc * NMAX;
        unsigned long long* pool =
            (unsigned long long*)(ws + F_POOL) + (size_t)bc * KMAX;
        const unsigned long long ctag = (unsigned long long)(cls << 12);
        #pragma unroll
        for (int w = 0; w < WMAX; ++w) {
            unsigned long long kwv = kw[w];
            int cc = w * 64 + lane;
            if (cc < n && ((kwv >> lane) & 1ull)) {
                int pos = pref[w] + __popcll(kwv & lmask);
                if (pos < KMAX) pool[pos] = gk[cc] | ctag;
            }
        }
    }

    /* zero image b's output slice, partitioned over its 20 blocks */
    {
        int idx = c * 256 + tid;
        if (idx < KMAX * 4) {
            out[OUT_BOXES + (size_t)b * KMAX * 4 + idx] = 0.0f;
        } else if (idx < KMAX * 4 + KMAX) {
            out[OUT_LABELS + b * KMAX + (idx - KMAX * 4)] = 0.0f;
        } else if (idx < KMAX * 4 + 2 * KMAX) {
            out[OUT_SCORES + b * KMAX + (idx - KMAX * 4 - KMAX)] = 0.0f;
        }
    }
}

/* K3b (R4 proven, VERBATIM): stage image pool into LDS, count (c==0),
   rank-select per class into global top-K, decode, write. */
__global__ __launch_bounds__(256)
void det_finishB(const float* __restrict__ locs, const float* __restrict__ priors,
                 const float* __restrict__ ws, float* __restrict__ out) {
    const int bc   = blockIdx.x;
    const int b    = bc / NCLS;
    const int c    = bc - b * NCLS;       /* 0..19 */
    const int tid  = threadIdx.x;

    __shared__ unsigned long long lpool[NCLS * KMAX];  /* 32 KB */
    __shared__ int cnts[NCLS];

    const int* cnt = (const int*)(ws + F_CNT);
    if (tid < NCLS) cnts[tid] = cnt[b * NCLS + tid];
    __syncthreads();

    const unsigned long long* pool =
        (const unsigned long long*)(ws + F_POOL) + (size_t)b * NCLS * KMAX;
    for (int i = tid; i < NCLS * KMAX; i += 256) {
        int c2 = i / KMAX, r = i - c2 * KMAX;
        int mc2 = cnts[c2] < KMAX ? cnts[c2] : KMAX;
        lpool[i] = (r < mc2) ? pool[i] : ~0ull;
    }
    __syncthreads();

    if (c == 0 && tid == 0) {
        int tot = 0;
        for (int c2 = 0; c2 < NCLS; ++c2) tot += cnts[c2];
        int count = tot < KMAX ? tot : KMAX;
        if (tot == 0) {
            float* ob = out + OUT_BOXES + (size_t)b * KMAX * 4;
            ob[0] = 0.0f; ob[1] = 0.0f; ob[2] = 1.0f; ob[3] = 1.0f;
            count = 1;
        }
        out[OUT_COUNTS + b] = (float)count;
    }

    const int mc = cnts[c] < KMAX ? cnts[c] : KMAX;
    if (tid < mc) {
        unsigned long long key = lpool[c * KMAX + tid];
        int rank = 0;
        #pragma unroll
        for (int c2 = 0; c2 < NCLS; ++c2) {
            int lo = 0, hi = KMAX;
            #pragma unroll
            for (int s = 0; s < 8; ++s) {          /* ceil(log2(201)) = 8 */
                int mid = (lo + hi) >> 1;
                int midc = mid < KMAX ? mid : KMAX - 1;
                unsigned long long v = lpool[c2 * KMAX + midc];
                bool lt = (lo < hi) && (v < key);
                lo = lt ? mid + 1 : lo;
                hi = lt ? hi : mid;
            }
            rank += lo;
        }
        if (rank < KMAX) {
            unsigned int lo32 = (unsigned int)key;
            int pi  = lo32 & 0xFFF;
            int lab = (lo32 >> 12) & 0x1F;
            float sc = __uint_as_float(~(unsigned int)(key >> 32));
            float x1, y1, x2, y2;
            decode_box(locs, priors, b, pi, x1, y1, x2, y2);
            float* ob = out + OUT_BOXES + ((size_t)b * KMAX + rank) * 4;
            ob[0] = x1; ob[1] = y1; ob[2] = x2; ob[3] = y2;
            out[OUT_LABELS + b * KMAX + rank] = (float)lab;
            out[OUT_SCORES + b * KMAX + rank] = sc;
        }
    }
}

extern "C" void kernel_launch(void* const* d_in, const int* in_sizes, int n_in,
                              void* d_out, int out_size, void* d_ws, size_t ws_size,
                              hipStream_t stream) {
    const float* locs   = (const float*)d_in[0];
    const float* scores = (const float*)d_in[1];
    const float* priors = (const float*)d_in[2];
    float* out = (float*)d_out;
    float* ws  = (float*)d_ws;

    det_softmax<<<(NB * NPRI + 255) / 256, 256, 0, stream>>>(scores, ws);
    det_prep<<<NB * NCLS, 1024, 0, stream>>>(locs, priors, ws);
    det_mbuild<<<dim3((TMAX + 3) / 4, NB * NCLS), 256, 0, stream>>>(ws);
    det_finishA<<<NB * NCLS, 256, 0, stream>>>(ws, out);
    det_finishB<<<NB * NCLS, 256, 0, stream>>>(locs, priors, ws, out);
}